// Round 7
// baseline (213.101 us; speedup 1.0000x reference)
//
#include <hip/hip_runtime.h>
#include <hip/hip_bf16.h>
#include <math.h>

#define BB 32
#define NN 512

typedef _Float16 f16x8 __attribute__((ext_vector_type(8)));
typedef float f32x4 __attribute__((ext_vector_type(4)));

#define MFMA16(a, b, c) __builtin_amdgcn_mfma_f32_16x16x32_f16(a, b, c, 0, 0, 0)

// ============ W^T fp16 prep (W0 + W1 fused), plain transpose ===============
// WT[n][k] = (fp16) W[k][n]
__global__ __launch_bounds__(256) void k_wt_prep(
    const float* __restrict__ W0, _Float16* __restrict__ W0T,
    const float* __restrict__ W1, _Float16* __restrict__ W1T)
{
    int id = blockIdx.x * 256 + threadIdx.x;   // 0..4607
    const float* W; _Float16* WT; int KT, task;
    if (id < 512) { W = W0; WT = W0T; KT = 64;  task = id; }
    else          { W = W1; WT = W1T; KT = 512; task = id - 512; }
    int n = task & 63, g = task >> 6;
    f16x8 hv;
#pragma unroll
    for (int e = 0; e < 8; ++e)
        hv[e] = (_Float16)W[(size_t)(g * 8 + e) * 64 + n];
    *(f16x8*)(WT + (size_t)n * KT + g * 8) = hv;
}

// ============ per-(b,h) max over j of dTg[b][h][j] ==========================
__global__ __launch_bounds__(256) void k_maxd(
    const float* __restrict__ dTg, float* __restrict__ maxd)
{
    __shared__ float sm[4];
    int bh = blockIdx.x;                       // 0..255
    int t = threadIdx.x, lane = t & 63, w = t >> 6;
    const float* p = dTg + (size_t)bh * NN;
    float m = fmaxf(p[t], p[t + 256]);
#pragma unroll
    for (int off = 32; off; off >>= 1) m = fmaxf(m, __shfl_xor(m, off));
    if (lane == 0) sm[w] = m;
    __syncthreads();
    if (t == 0) maxd[bh] = fmaxf(fmaxf(sm[0], sm[1]), fmaxf(sm[2], sm[3]));
}

// ============ shared epilogue: 16x66 fp32 ctile -> s, dTg, fp16 hpT =========
static __device__ __forceinline__ void epi_sd_hpt(
    const float* ctile, const float* asd_f, int row0, int t,
    float* __restrict__ s, float* __restrict__ dTg, _Float16* __restrict__ hpT)
{
    int b = row0 >> 9, jb = row0 & 511;
    if (t < 128) {
        int rr = t >> 3, h = t & 7;
        float sv = 0.f, dv = 0.f;
#pragma unroll
        for (int f = 0; f < 64; ++f) {
            float hv = ctile[rr * 66 + f];
            sv = fmaf(hv, asd_f[f * 8 + h], sv);
            dv = fmaf(hv, asd_f[512 + f * 8 + h], dv);
        }
        s[((size_t)b * NN + jb + rr) * 8 + h] = sv;
        dTg[((size_t)b * 8 + h) * NN + jb + rr] = dv;
    } else {
        int t2 = t - 128;
        int f = t2 >> 1, jl = (t2 & 1) * 8;
        f16x8 hv;
#pragma unroll
        for (int e = 0; e < 8; ++e)
            hv[e] = (_Float16)ctile[(jl + e) * 66 + f];
        *(f16x8*)(hpT + ((size_t)b * 64 + f) * NN + jb + jl) = hv;
    }
}

// ============ Layer-0 GEMM: global-direct fp16, 16 rows/block ===============
__global__ __launch_bounds__(256) void k_gemm0(
    const float* __restrict__ x, const _Float16* __restrict__ W0T,
    const float* __restrict__ a_src, const float* __restrict__ a_dst,
    float* __restrict__ s, float* __restrict__ dTg, _Float16* __restrict__ hpT)
{
    __shared__ float ctile[16 * 66];
    __shared__ float asd_f[1024];
    int t = threadIdx.x, row0 = blockIdx.x * 16;
    int lane = t & 63, w = t >> 6, cn = lane & 15, rq = lane >> 4;

    ((float4*)asd_f)[t] = (t < 128) ? ((const float4*)a_src)[t]
                                    : ((const float4*)a_dst)[t - 128];
    f32x4 acc;
#pragma unroll
    for (int e = 0; e < 4; ++e) acc[e] = 0.f;
#pragma unroll
    for (int ks = 0; ks < 2; ++ks) {
        const float* xp = x + (size_t)(row0 + cn) * 64 + ks * 32 + rq * 8;
        float4 x0 = *(const float4*)xp, x1 = *(const float4*)(xp + 4);
        f16x8 ah = {(_Float16)x0.x, (_Float16)x0.y, (_Float16)x0.z, (_Float16)x0.w,
                    (_Float16)x1.x, (_Float16)x1.y, (_Float16)x1.z, (_Float16)x1.w};
        f16x8 bh = *(const f16x8*)(W0T + (size_t)(w * 16 + cn) * 64 + ks * 32 + rq * 8);
        acc = MFMA16(ah, bh, acc);
    }
#pragma unroll
    for (int r = 0; r < 4; ++r)
        ctile[(rq * 4 + r) * 66 + w * 16 + cn] = acc[r];
    __syncthreads();
    epi_sd_hpt(ctile, asd_f, row0, t, s, dTg, hpT);
}

// ============ fused attention: ZERO barriers / ZERO LDS in the K-loop =======
// Lane (cn,rq) of wave w builds P'[row=cn][j=rq*8+e] for heads 2w,2w+1 in
// registers from global adj/dTg, reads hp B-fragments straight from L2-hot
// fp16 hpT, accumulates PV + rowsum (B=ones) on the matrix pipe.
// MODE 0: + on-chip gemm1 vs W1T (global B), epilogue s1/dTg1/hp1T.
// MODE 1: head-mean fp32 out.
template<int MODE>
__global__ __launch_bounds__(256, 4) void k_attn_fused(
    const float* __restrict__ adj, const float* __restrict__ s,
    const float* __restrict__ dTg, const float* __restrict__ maxd,
    const _Float16* __restrict__ hpT,
    const _Float16* __restrict__ W1T,
    const float* __restrict__ a_src, const float* __restrict__ a_dst,
    float* __restrict__ s_out, float* __restrict__ dTg_out,
    _Float16* __restrict__ hpT_out, float* __restrict__ o_f)
{
    __shared__ __align__(16) char smem[16384];

    int blk = blockIdx.x;
    int vb = ((blk & 7) << 7) | (blk >> 3);    // XCD swizzle: 4 batches/XCD
    int b = vb >> 5, i0 = (vb & 31) << 4;
    int row0 = vb * 16;                        // = b*512 + i0
    int t = threadIdx.x, lane = t & 63, w = t >> 6;
    int cn = lane & 15, rq = lane >> 4;
    int h0 = 2 * w, h1 = h0 + 1;
    int myrow = i0 + cn;

    float sv0 = s[((size_t)b * NN + myrow) * 8 + h0];
    float sv1 = s[((size_t)b * NN + myrow) * 8 + h1];
    float M0 = fmaxf(sv0 + maxd[b * 8 + h0], 0.f);
    float M1 = fmaxf(sv1 + maxd[b * 8 + h1], 0.f);

    const float* arow = adj + ((size_t)b * NN + myrow) * NN;
    const float* dg0 = dTg + ((size_t)b * 8 + h0) * NN;
    const float* dg1 = dTg + ((size_t)b * 8 + h1) * NN;
    const _Float16* hb = hpT + (size_t)b * 64 * NN;

    f16x8 ones;
#pragma unroll
    for (int e = 0; e < 8; ++e) ones[e] = (_Float16)1.0f;

    f32x4 acc[2][4], accrs[2];
#pragma unroll
    for (int hh = 0; hh < 2; ++hh) {
#pragma unroll
        for (int e = 0; e < 4; ++e) accrs[hh][e] = 0.f;
#pragma unroll
        for (int ft = 0; ft < 4; ++ft)
#pragma unroll
            for (int e = 0; e < 4; ++e) acc[hh][ft][e] = 0.f;
    }

    for (int jc = 0; jc < NN; jc += 64) {
#pragma unroll
        for (int ks = 0; ks < 2; ++ks) {
            int j0 = jc + ks * 32 + rq * 8;
            float4 a0 = *(const float4*)(arow + j0);
            float4 a1 = *(const float4*)(arow + j0 + 4);
            float4 d00 = *(const float4*)(dg0 + j0);
            float4 d01 = *(const float4*)(dg0 + j0 + 4);
            float4 d10 = *(const float4*)(dg1 + j0);
            float4 d11 = *(const float4*)(dg1 + j0 + 4);
            float aa[8]  = {a0.x, a0.y, a0.z, a0.w, a1.x, a1.y, a1.z, a1.w};
            float dd0[8] = {d00.x, d00.y, d00.z, d00.w, d01.x, d01.y, d01.z, d01.w};
            float dd1[8] = {d10.x, d10.y, d10.z, d10.w, d11.x, d11.y, d11.z, d11.w};
            int rel = myrow - j0;              // self-loop at e == rel
            f16x8 aA, aB;
#pragma unroll
            for (int e = 0; e < 8; ++e) {
                bool con = (aa[e] != 0.f) || (e == rel);
                float e0 = sv0 + dd0[e];
                float l0 = fmaxf(e0, 0.2f * e0);
                float p0 = __expf(l0 - M0);
                p0 = (con && l0 != 0.f) ? p0 : 0.f;   // mask + exact-0 quirk
                float e1 = sv1 + dd1[e];
                float l1 = fmaxf(e1, 0.2f * e1);
                float p1 = __expf(l1 - M1);
                p1 = (con && l1 != 0.f) ? p1 : 0.f;
                aA[e] = (_Float16)p0;
                aB[e] = (_Float16)p1;
            }
            accrs[0] = MFMA16(aA, ones, accrs[0]);
            accrs[1] = MFMA16(aB, ones, accrs[1]);
#pragma unroll
            for (int ft = 0; ft < 4; ++ft) {
                f16x8 bh = *(const f16x8*)(hb + (size_t)(ft * 16 + cn) * NN + j0);
                acc[0][ft] = MFMA16(aA, bh, acc[0][ft]);
                acc[1][ft] = MFMA16(aB, bh, acc[1][ft]);
            }
        }
    }

    float invr[2][4];
#pragma unroll
    for (int hh = 0; hh < 2; ++hh)
#pragma unroll
        for (int r = 0; r < 4; ++r) invr[hh][r] = 1.0f / accrs[hh][r];

    if (MODE == 0) {
        // ---- x1 tiles (normalized + ELU) into LDS, A-layout, XOR-swizzled
        _Float16* x1all = (_Float16*)smem;     // [8 heads][16*64]
#pragma unroll
        for (int hh = 0; hh < 2; ++hh) {
            int h = h0 + hh;
#pragma unroll
            for (int ft = 0; ft < 4; ++ft)
#pragma unroll
                for (int r = 0; r < 4; ++r) {
                    int il = rq * 4 + r;
                    float v = acc[hh][ft][r] * invr[hh][r];
                    v = v > 0.f ? v : __expf(v) - 1.f;   // ELU
                    int f = ft * 16 + cn;
                    x1all[h * 1024 + il * 64 + (((f >> 3) ^ (il & 7)) * 8) + (f & 7)] =
                        (_Float16)v;
                }
        }
        __syncthreads();

        // ---- gemm1: A from LDS x1all, B straight from L2-hot W1T; no barriers
        f32x4 g1;
#pragma unroll
        for (int e = 0; e < 4; ++e) g1[e] = 0.f;
        for (int kc = 0; kc < 8; ++kc) {
#pragma unroll
            for (int ks = 0; ks < 2; ++ks) {
                int pa = (((ks * 4 + rq) ^ (cn & 7)) * 8);
                f16x8 ah = *(const f16x8*)&x1all[kc * 1024 + cn * 64 + pa];
                f16x8 bh = *(const f16x8*)(W1T + (size_t)(w * 16 + cn) * 512 + kc * 64 + ks * 32 + rq * 8);
                g1 = MFMA16(ah, bh, g1);
            }
        }
        __syncthreads();                       // x1all dead -> reuse as ctile/asd
        float* ctile = (float*)smem;           // 4224 B
        float* asd_f = (float*)(smem + 4352);  // 4096 B
#pragma unroll
        for (int r = 0; r < 4; ++r)
            ctile[(rq * 4 + r) * 66 + w * 16 + cn] = g1[r];
        ((float4*)asd_f)[t] = (t < 128) ? ((const float4*)a_src)[t]
                                        : ((const float4*)a_dst)[t - 128];
        __syncthreads();
        epi_sd_hpt(ctile, asd_f, row0, t, s_out, dTg_out, hpT_out);
    } else {
        float* red = (float*)smem;             // [4][16][64] fp32 = 16 KB
#pragma unroll
        for (int ft = 0; ft < 4; ++ft)
#pragma unroll
            for (int r = 0; r < 4; ++r) {
                int il = rq * 4 + r;
                float v = acc[0][ft][r] * invr[0][r]
                        + acc[1][ft][r] * invr[1][r];
                red[(w * 16 + il) * 64 + ft * 16 + cn] = v;
            }
        __syncthreads();
#pragma unroll
        for (int u = 0; u < 4; ++u) {
            int idx = t + u * 256;
            int il = idx >> 6, f = idx & 63;
            float sum = red[il * 64 + f] + red[(16 + il) * 64 + f]
                      + red[(32 + il) * 64 + f] + red[(48 + il) * 64 + f];
            o_f[((size_t)b * NN + i0 + il) * 64 + f] = sum * 0.125f;
        }
    }
}

extern "C" void kernel_launch(void* const* d_in, const int* in_sizes, int n_in,
                              void* d_out, int out_size, void* d_ws, size_t ws_size,
                              hipStream_t stream) {
    const float* x      = (const float*)d_in[0];
    const float* adj    = (const float*)d_in[1];
    const float* W0     = (const float*)d_in[4];
    const float* a_src0 = (const float*)d_in[5];
    const float* a_dst0 = (const float*)d_in[6];
    const float* W1     = (const float*)d_in[7];
    const float* a_src1 = (const float*)d_in[8];
    const float* a_dst1 = (const float*)d_in[9];
    float* out = (float*)d_out;

    float* ws = (float*)d_ws;
    const size_t R = (size_t)BB * NN;            // 16384 rows
    float* s0    = ws;                           // R*8
    float* dTg0  = s0 + R * 8;                   // 32*8*512
    float* s1    = dTg0 + (size_t)BB * 8 * NN;
    float* dTg1  = s1 + R * 8;
    float* maxd0 = dTg1 + (size_t)BB * 8 * NN;   // 256
    float* maxd1 = maxd0 + 256;                  // 256
    _Float16* hp0T = (_Float16*)(maxd1 + 256);   // 32*64*512
    _Float16* hp1T = hp0T + (size_t)BB * 64 * NN;
    _Float16* W0T  = hp1T + (size_t)BB * 64 * NN;   // 64*64
    _Float16* W1T  = W0T + (size_t)64 * 64;         // 64*512

    k_wt_prep<<<18, 256, 0, stream>>>(W0, W0T, W1, W1T);
    k_gemm0<<<1024, 256, 0, stream>>>(x, W0T, a_src0, a_dst0, s0, dTg0, hp0T);
    k_maxd<<<256, 256, 0, stream>>>(dTg0, maxd0);
    k_attn_fused<0><<<1024, 256, 0, stream>>>(adj, s0, dTg0, maxd0, hp0T,
                                              W1T, a_src1, a_dst1,
                                              s1, dTg1, hp1T, nullptr);
    k_maxd<<<256, 256, 0, stream>>>(dTg1, maxd1);
    k_attn_fused<1><<<1024, 256, 0, stream>>>(adj, s1, dTg1, maxd1, hp1T,
                                              nullptr, nullptr, nullptr,
                                              nullptr, nullptr, nullptr, out);
}

// Round 9
// 174.628 us; speedup vs baseline: 1.2203x; 1.2203x over previous
//
#include <hip/hip_runtime.h>
#include <hip/hip_bf16.h>
#include <math.h>

#define BB 32
#define NN 512

typedef _Float16 f16x8 __attribute__((ext_vector_type(8)));
typedef float f32x4 __attribute__((ext_vector_type(4)));

#define MFMA16(a, b, c) __builtin_amdgcn_mfma_f32_16x16x32_f16(a, b, c, 0, 0, 0)

// ============ W^T fp16 prep (W0 + W1 fused), XOR-swizzled granules =========
// Stores logical granule g of row n at physical granule g^(n&7).
// Consumers that read global directly (gemm0) or copy physically into LDS
// (gemm1 staging) then use swizzle-aware fragment reads.
__global__ __launch_bounds__(256) void k_wt_prep(
    const float* __restrict__ W0, _Float16* __restrict__ W0T,
    const float* __restrict__ W1, _Float16* __restrict__ W1T)
{
    int id = blockIdx.x * 256 + threadIdx.x;   // 0..4607
    const float* W; _Float16* WT; int KT, task;
    if (id < 512) { W = W0; WT = W0T; KT = 64;  task = id; }
    else          { W = W1; WT = W1T; KT = 512; task = id - 512; }
    int n = task & 63, gabs = task >> 6;
    int c = gabs >> 3, g = gabs & 7;
    f16x8 hv;
#pragma unroll
    for (int e = 0; e < 8; ++e)
        hv[e] = (_Float16)W[(size_t)(gabs * 8 + e) * 64 + n];
    *(f16x8*)(WT + (size_t)n * KT + c * 64 + (g ^ (n & 7)) * 8) = hv;
}

// ============ per-(b,h) max over j of dTg[b][h][j] ==========================
__global__ __launch_bounds__(256) void k_maxd(
    const float* __restrict__ dTg, float* __restrict__ maxd)
{
    __shared__ float sm[4];
    int bh = blockIdx.x;                       // 0..255
    int t = threadIdx.x, lane = t & 63, w = t >> 6;
    const float* p = dTg + (size_t)bh * NN;
    float m = fmaxf(p[t], p[t + 256]);
#pragma unroll
    for (int off = 32; off; off >>= 1) m = fmaxf(m, __shfl_xor(m, off));
    if (lane == 0) sm[w] = m;
    __syncthreads();
    if (t == 0) maxd[bh] = fmaxf(fmaxf(sm[0], sm[1]), fmaxf(sm[2], sm[3]));
}

// ============ shared epilogue: 16x66 fp32 ctile -> s, dTg, fp16 hpT =========
// hpT layout: plain [b][f][j] fp16 (consumer swizzles while staging to LDS)
static __device__ __forceinline__ void epi_sd_hpt(
    const float* ctile, const float* asd_f, int row0, int t,
    float* __restrict__ s, float* __restrict__ dTg, _Float16* __restrict__ hpT)
{
    int b = row0 >> 9, jb = row0 & 511;
    if (t < 128) {
        int rr = t >> 3, h = t & 7;
        float sv = 0.f, dv = 0.f;
#pragma unroll
        for (int f = 0; f < 64; ++f) {
            float hv = ctile[rr * 66 + f];
            sv = fmaf(hv, asd_f[f * 8 + h], sv);
            dv = fmaf(hv, asd_f[512 + f * 8 + h], dv);
        }
        s[((size_t)b * NN + jb + rr) * 8 + h] = sv;
        dTg[((size_t)b * 8 + h) * NN + jb + rr] = dv;
    } else {
        int t2 = t - 128;
        int f = t2 >> 1, jl = (t2 & 1) * 8;
        f16x8 hv;
#pragma unroll
        for (int e = 0; e < 8; ++e)
            hv[e] = (_Float16)ctile[(jl + e) * 66 + f];
        *(f16x8*)(hpT + ((size_t)b * 64 + f) * NN + jb + jl) = hv;
    }
}

// ============ Layer-0 GEMM: fp16 MFMA, 16 rows/block, K=64 ==================
__global__ __launch_bounds__(256) void k_gemm0(
    const float* __restrict__ x, const _Float16* __restrict__ W0T,
    const float* __restrict__ a_src, const float* __restrict__ a_dst,
    float* __restrict__ s, float* __restrict__ dTg, _Float16* __restrict__ hpT)
{
    __shared__ float ctile[16 * 66];
    __shared__ float asd_f[1024];
    int t = threadIdx.x, row0 = blockIdx.x * 16;
    int lane = t & 63, w = t >> 6, cn = lane & 15, rq = lane >> 4;

    ((float4*)asd_f)[t] = (t < 128) ? ((const float4*)a_src)[t]
                                    : ((const float4*)a_dst)[t - 128];
    f32x4 acc;
#pragma unroll
    for (int e = 0; e < 4; ++e) acc[e] = 0.f;
#pragma unroll
    for (int ks = 0; ks < 2; ++ks) {
        const float* xp = x + (size_t)(row0 + cn) * 64 + ks * 32 + rq * 8;
        float4 x0 = *(const float4*)xp, x1 = *(const float4*)(xp + 4);
        f16x8 ah = {(_Float16)x0.x, (_Float16)x0.y, (_Float16)x0.z, (_Float16)x0.w,
                    (_Float16)x1.x, (_Float16)x1.y, (_Float16)x1.z, (_Float16)x1.w};
        int nn = w * 16 + cn;
        f16x8 bh = *(const f16x8*)(W0T + (size_t)nn * 64 + (((ks * 4 + rq) ^ (nn & 7)) * 8));
        acc = MFMA16(ah, bh, acc);
    }
#pragma unroll
    for (int r = 0; r < 4; ++r)
        ctile[(rq * 4 + r) * 66 + w * 16 + cn] = acc[r];
    __syncthreads();
    epi_sd_hpt(ctile, asd_f, row0, t, s, dTg, hpT);
}

// ============ fused attention v4: fp16 + LDS-staged MFMA operands ===========
// Per 64-j chunk: stage hT (8KB, plain->swizzled) in LDS; P-build from global
// adj/dTg in registers; PV + rowsum (B=ones) on the matrix pipe from LDS.
// MODE 0: + gemm1 vs LDS-staged W1T (already-swizzled global -> straight
//         physical copy), epilogue s1/dTg1/hp1T.
// MODE 1: head-mean fp32 out.
template<int MODE>
__global__ __launch_bounds__(256, 4) void k_attn_fused(
    const float* __restrict__ adj, const float* __restrict__ s,
    const float* __restrict__ dTg, const float* __restrict__ maxd,
    const _Float16* __restrict__ hpT,
    const _Float16* __restrict__ W1T,
    const float* __restrict__ a_src, const float* __restrict__ a_dst,
    float* __restrict__ s_out, float* __restrict__ dTg_out,
    _Float16* __restrict__ hpT_out, float* __restrict__ o_f)
{
    __shared__ __align__(16) char smem[32768];
    _Float16* hT = (_Float16*)smem;            // [64][64] swizzled fp16, 8KB

    int blk = blockIdx.x;
    int vb = ((blk & 7) << 7) | (blk >> 3);    // XCD swizzle: 4 batches/XCD
    int b = vb >> 5, i0 = (vb & 31) << 4;
    int row0 = vb * 16;                        // = b*512 + i0
    int t = threadIdx.x, lane = t & 63, w = t >> 6;
    int cn = lane & 15, rq = lane >> 4;
    int h0 = 2 * w, h1 = h0 + 1;
    int myrow = i0 + cn;

    float sv0 = s[((size_t)b * NN + myrow) * 8 + h0];
    float sv1 = s[((size_t)b * NN + myrow) * 8 + h1];
    float M0 = fmaxf(sv0 + maxd[b * 8 + h0], 0.f);
    float M1 = fmaxf(sv1 + maxd[b * 8 + h1], 0.f);

    const float* arow = adj + ((size_t)b * NN + myrow) * NN;
    const float* dg0 = dTg + ((size_t)b * 8 + h0) * NN;
    const float* dg1 = dTg + ((size_t)b * 8 + h1) * NN;
    const _Float16* hb = hpT + (size_t)b * 64 * NN;

    f16x8 ones;
#pragma unroll
    for (int e = 0; e < 8; ++e) ones[e] = (_Float16)1.0f;

    f32x4 acc[2][4], accrs[2];
#pragma unroll
    for (int hh = 0; hh < 2; ++hh) {
#pragma unroll
        for (int e = 0; e < 4; ++e) accrs[hh][e] = 0.f;
#pragma unroll
        for (int ft = 0; ft < 4; ++ft)
#pragma unroll
            for (int e = 0; e < 4; ++e) acc[hh][ft][e] = 0.f;
    }

    for (int jc = 0; jc < NN; jc += 64) {
        // ---- stage hT chunk: 64 f-rows x 64 j fp16, plain -> XOR-swizzled
#pragma unroll
        for (int u = 0; u < 2; ++u) {
            int idx = t + u * 256;
            int f = idx >> 3, g = idx & 7;
            *(uint4*)&hT[f * 64 + ((g ^ (f & 7)) * 8)] =
                *(const uint4*)(hb + (size_t)f * 512 + jc + g * 8);
        }
        __syncthreads();

        // ---- batched global reads for P-build (independent of hT)
        float aa[2][8], dd0[2][8], dd1[2][8];
#pragma unroll
        for (int ks = 0; ks < 2; ++ks) {
            int j0 = jc + ks * 32 + rq * 8;
            *(float4*)&aa[ks][0]  = *(const float4*)(arow + j0);
            *(float4*)&aa[ks][4]  = *(const float4*)(arow + j0 + 4);
            *(float4*)&dd0[ks][0] = *(const float4*)(dg0 + j0);
            *(float4*)&dd0[ks][4] = *(const float4*)(dg0 + j0 + 4);
            *(float4*)&dd1[ks][0] = *(const float4*)(dg1 + j0);
            *(float4*)&dd1[ks][4] = *(const float4*)(dg1 + j0 + 4);
        }
#pragma unroll
        for (int ks = 0; ks < 2; ++ks) {
            int j0 = jc + ks * 32 + rq * 8;
            int rel = myrow - j0;              // self-loop at e == rel
            f16x8 aA, aB;
#pragma unroll
            for (int e = 0; e < 8; ++e) {
                bool con = (aa[ks][e] != 0.f) || (e == rel);
                float e0 = sv0 + dd0[ks][e];
                float l0 = fmaxf(e0, 0.2f * e0);
                float p0 = __expf(l0 - M0);
                p0 = (con && l0 != 0.f) ? p0 : 0.f;   // mask + exact-0 quirk
                float e1 = sv1 + dd1[ks][e];
                float l1 = fmaxf(e1, 0.2f * e1);
                float p1 = __expf(l1 - M1);
                p1 = (con && l1 != 0.f) ? p1 : 0.f;
                aA[e] = (_Float16)p0;
                aB[e] = (_Float16)p1;
            }
            accrs[0] = MFMA16(aA, ones, accrs[0]);
            accrs[1] = MFMA16(aB, ones, accrs[1]);
#pragma unroll
            for (int ft = 0; ft < 4; ++ft) {
                int f = ft * 16 + cn;
                f16x8 bh = *(const f16x8*)&hT[f * 64 + (((ks * 4 + rq) ^ (f & 7)) * 8)];
                acc[0][ft] = MFMA16(aA, bh, acc[0][ft]);
                acc[1][ft] = MFMA16(aB, bh, acc[1][ft]);
            }
        }
        __syncthreads();
    }

    float invr[2][4];
#pragma unroll
    for (int hh = 0; hh < 2; ++hh)
#pragma unroll
        for (int r = 0; r < 4; ++r) invr[hh][r] = 1.0f / accrs[hh][r];

    if (MODE == 0) {
        // ---- x1 tiles (normalized + ELU) into LDS, A-layout, XOR-swizzled
        _Float16* x1all = (_Float16*)(smem + 8192);    // [8 heads][16*64], 16KB
#pragma unroll
        for (int hh = 0; hh < 2; ++hh) {
            int h = h0 + hh;
#pragma unroll
            for (int ft = 0; ft < 4; ++ft)
#pragma unroll
                for (int r = 0; r < 4; ++r) {
                    int il = rq * 4 + r;
                    float v = acc[hh][ft][r] * invr[hh][r];
                    v = v > 0.f ? v : __expf(v) - 1.f;   // ELU
                    int f = ft * 16 + cn;
                    x1all[h * 1024 + il * 64 + (((f >> 3) ^ (il & 7)) * 8) + (f & 7)] =
                        (_Float16)v;
                }
        }

        // ---- gemm1: A from LDS x1all, B = W1T chunks ping/pong through LDS.
        // Global W1T is ALREADY swizzled -> straight physical copy into LDS.
        _Float16* Bst[2] = { (_Float16*)smem, (_Float16*)(smem + 24576) };
        {   // stage kc=0 into ping (hT dead after barrier below)
            __syncthreads();
#pragma unroll
            for (int u = 0; u < 2; ++u) {
                int idx = t + u * 256;        // idx*8 = n*64 + g*8 (physical)
                *(uint4*)&Bst[0][idx * 8] =
                    *(const uint4*)(W1T + (size_t)(idx >> 3) * 512 + (idx & 7) * 8);
            }
        }
        f32x4 g1;
#pragma unroll
        for (int e = 0; e < 4; ++e) g1[e] = 0.f;
        for (int kc = 0; kc < 8; ++kc) {
            int cur = kc & 1;
            __syncthreads();
            if (kc < 7) {
#pragma unroll
                for (int u = 0; u < 2; ++u) {
                    int idx = t + u * 256;
                    *(uint4*)&Bst[cur ^ 1][idx * 8] =
                        *(const uint4*)(W1T + (size_t)(idx >> 3) * 512 + (kc + 1) * 64 + (idx & 7) * 8);
                }
            }
#pragma unroll
            for (int ks = 0; ks < 2; ++ks) {
                int pa = (((ks * 4 + rq) ^ (cn & 7)) * 8);
                f16x8 ah = *(const f16x8*)&x1all[kc * 1024 + cn * 64 + pa];
                int nn = w * 16 + cn;
                f16x8 bh = *(const f16x8*)&Bst[cur][nn * 64 + (((ks * 4 + rq) ^ (nn & 7)) * 8)];
                g1 = MFMA16(ah, bh, g1);
            }
        }
        __syncthreads();                       // x1all dead -> reuse region
        float* ctile = (float*)(smem + 8192);  // 4224 B
        float* asd_f = (float*)(smem + 16384); // 4096 B
#pragma unroll
        for (int r = 0; r < 4; ++r)
            ctile[(rq * 4 + r) * 66 + w * 16 + cn] = g1[r];
        ((float4*)asd_f)[t] = (t < 128) ? ((const float4*)a_src)[t]
                                        : ((const float4*)a_dst)[t - 128];
        __syncthreads();
        epi_sd_hpt(ctile, asd_f, row0, t, s_out, dTg_out, hpT_out);
    } else {
        float* red = (float*)smem;             // [4][16][64] fp32 = 16 KB
#pragma unroll
        for (int ft = 0; ft < 4; ++ft)
#pragma unroll
            for (int r = 0; r < 4; ++r) {
                int il = rq * 4 + r;
                float v = acc[0][ft][r] * invr[0][r]
                        + acc[1][ft][r] * invr[1][r];
                red[(w * 16 + il) * 64 + ft * 16 + cn] = v;
            }
        __syncthreads();
#pragma unroll
        for (int u = 0; u < 4; ++u) {
            int idx = t + u * 256;
            int il = idx >> 6, f = idx & 63;
            float sum = red[il * 64 + f] + red[(16 + il) * 64 + f]
                      + red[(32 + il) * 64 + f] + red[(48 + il) * 64 + f];
            o_f[((size_t)b * NN + i0 + il) * 64 + f] = sum * 0.125f;
        }
    }
}

extern "C" void kernel_launch(void* const* d_in, const int* in_sizes, int n_in,
                              void* d_out, int out_size, void* d_ws, size_t ws_size,
                              hipStream_t stream) {
    const float* x      = (const float*)d_in[0];
    const float* adj    = (const float*)d_in[1];
    const float* W0     = (const float*)d_in[4];
    const float* a_src0 = (const float*)d_in[5];
    const float* a_dst0 = (const float*)d_in[6];
    const float* W1     = (const float*)d_in[7];
    const float* a_src1 = (const float*)d_in[8];
    const float* a_dst1 = (const float*)d_in[9];
    float* out = (float*)d_out;

    float* ws = (float*)d_ws;
    const size_t R = (size_t)BB * NN;            // 16384 rows
    float* s0    = ws;                           // R*8
    float* dTg0  = s0 + R * 8;                   // 32*8*512
    float* s1    = dTg0 + (size_t)BB * 8 * NN;
    float* dTg1  = s1 + R * 8;
    float* maxd0 = dTg1 + (size_t)BB * 8 * NN;   // 256
    float* maxd1 = maxd0 + 256;                  // 256
    _Float16* hp0T = (_Float16*)(maxd1 + 256);   // 32*64*512
    _Float16* hp1T = hp0T + (size_t)BB * 64 * NN;
    _Float16* W0T  = hp1T + (size_t)BB * 64 * NN;   // 64*64
    _Float16* W1T  = W0T + (size_t)64 * 64;         // 64*512

    k_wt_prep<<<18, 256, 0, stream>>>(W0, W0T, W1, W1T);
    k_gemm0<<<1024, 256, 0, stream>>>(x, W0T, a_src0, a_dst0, s0, dTg0, hp0T);
    k_maxd<<<256, 256, 0, stream>>>(dTg0, maxd0);
    k_attn_fused<0><<<1024, 256, 0, stream>>>(adj, s0, dTg0, maxd0, hp0T,
                                              W1T, a_src1, a_dst1,
                                              s1, dTg1, hp1T, nullptr);
    k_maxd<<<256, 256, 0, stream>>>(dTg1, maxd1);
    k_attn_fused<1><<<1024, 256, 0, stream>>>(adj, s1, dTg1, maxd1, hp1T,
                                              nullptr, nullptr, nullptr,
                                              nullptr, nullptr, nullptr, out);
}

// Round 11
// 165.129 us; speedup vs baseline: 1.2905x; 1.0575x over previous
//
#include <hip/hip_runtime.h>
#include <hip/hip_bf16.h>
#include <math.h>

#define BB 32
#define NN 512

typedef _Float16 f16x8 __attribute__((ext_vector_type(8)));
typedef __fp16  fp16x2 __attribute__((ext_vector_type(2)));
typedef float f32x4 __attribute__((ext_vector_type(4)));

#define MFMA16(a, b, c) __builtin_amdgcn_mfma_f32_16x16x32_f16(a, b, c, 0, 0, 0)

union AF { f16x8 v; unsigned int u[4]; };

// ============ W^T fp16 prep (W0 + W1 fused), XOR-swizzled granules =========
// Stores logical granule g of row n at physical granule g^(n&7).
__global__ __launch_bounds__(256) void k_wt_prep(
    const float* __restrict__ W0, _Float16* __restrict__ W0T,
    const float* __restrict__ W1, _Float16* __restrict__ W1T)
{
    int id = blockIdx.x * 256 + threadIdx.x;   // 0..4607
    const float* W; _Float16* WT; int KT, task;
    if (id < 512) { W = W0; WT = W0T; KT = 64;  task = id; }
    else          { W = W1; WT = W1T; KT = 512; task = id - 512; }
    int n = task & 63, gabs = task >> 6;
    int c = gabs >> 3, g = gabs & 7;
    f16x8 hv;
#pragma unroll
    for (int e = 0; e < 8; ++e)
        hv[e] = (_Float16)W[(size_t)(gabs * 8 + e) * 64 + n];
    *(f16x8*)(WT + (size_t)n * KT + c * 64 + (g ^ (n & 7)) * 8) = hv;
}

// ============ per-(b,h) max over j of dTg[b][h][j] ==========================
__global__ __launch_bounds__(256) void k_maxd(
    const float* __restrict__ dTg, float* __restrict__ maxd)
{
    __shared__ float sm[4];
    int bh = blockIdx.x;                       // 0..255
    int t = threadIdx.x, lane = t & 63, w = t >> 6;
    const float* p = dTg + (size_t)bh * NN;
    float m = fmaxf(p[t], p[t + 256]);
#pragma unroll
    for (int off = 32; off; off >>= 1) m = fmaxf(m, __shfl_xor(m, off));
    if (lane == 0) sm[w] = m;
    __syncthreads();
    if (t == 0) maxd[bh] = fmaxf(fmaxf(sm[0], sm[1]), fmaxf(sm[2], sm[3]));
}

// ============ shared epilogue: 16x66 fp32 ctile -> s, dTg, fp16 hpT =========
static __device__ __forceinline__ void epi_sd_hpt(
    const float* ctile, const float* asd_f, int row0, int t,
    float* __restrict__ s, float* __restrict__ dTg, _Float16* __restrict__ hpT)
{
    int b = row0 >> 9, jb = row0 & 511;
    if (t < 128) {
        int rr = t >> 3, h = t & 7;
        float sv = 0.f, dv = 0.f;
#pragma unroll
        for (int f = 0; f < 64; ++f) {
            float hv = ctile[rr * 66 + f];
            sv = fmaf(hv, asd_f[f * 8 + h], sv);
            dv = fmaf(hv, asd_f[512 + f * 8 + h], dv);
        }
        s[((size_t)b * NN + jb + rr) * 8 + h] = sv;
        dTg[((size_t)b * 8 + h) * NN + jb + rr] = dv;
    } else {
        int t2 = t - 128;
        int f = t2 >> 1, jl = (t2 & 1) * 8;
        f16x8 hv;
#pragma unroll
        for (int e = 0; e < 8; ++e)
            hv[e] = (_Float16)ctile[(jl + e) * 66 + f];
        *(f16x8*)(hpT + ((size_t)b * 64 + f) * NN + jb + jl) = hv;
    }
}

// ============ Layer-0 GEMM: fp16 MFMA, 16 rows/block, K=64 ==================
__global__ __launch_bounds__(256) void k_gemm0(
    const float* __restrict__ x, const _Float16* __restrict__ W0T,
    const float* __restrict__ a_src, const float* __restrict__ a_dst,
    float* __restrict__ s, float* __restrict__ dTg, _Float16* __restrict__ hpT)
{
    __shared__ float ctile[16 * 66];
    __shared__ float asd_f[1024];
    int t = threadIdx.x, row0 = blockIdx.x * 16;
    int lane = t & 63, w = t >> 6, cn = lane & 15, rq = lane >> 4;

    ((float4*)asd_f)[t] = (t < 128) ? ((const float4*)a_src)[t]
                                    : ((const float4*)a_dst)[t - 128];
    f32x4 acc;
#pragma unroll
    for (int e = 0; e < 4; ++e) acc[e] = 0.f;
#pragma unroll
    for (int ks = 0; ks < 2; ++ks) {
        const float* xp = x + (size_t)(row0 + cn) * 64 + ks * 32 + rq * 8;
        float4 x0 = *(const float4*)xp, x1 = *(const float4*)(xp + 4);
        f16x8 ah = {(_Float16)x0.x, (_Float16)x0.y, (_Float16)x0.z, (_Float16)x0.w,
                    (_Float16)x1.x, (_Float16)x1.y, (_Float16)x1.z, (_Float16)x1.w};
        int nn = w * 16 + cn;
        f16x8 bh = *(const f16x8*)(W0T + (size_t)nn * 64 + (((ks * 4 + rq) ^ (nn & 7)) * 8));
        acc = MFMA16(ah, bh, acc);
    }
#pragma unroll
    for (int r = 0; r < 4; ++r)
        ctile[(rq * 4 + r) * 66 + w * 16 + cn] = acc[r];
    __syncthreads();
    epi_sd_hpt(ctile, asd_f, row0, t, s, dTg, hpT);
}

// ============ fused attention v5: software-pipelined K-loop =================
// Per 64-j chunk: adj/d loads issue BEFORE the staging barrier; hT staged via
// register prefetch (loads for jc+1 issue right after jc's barrier); P-build
// packed via cvt_pkrtz; PV + rowsum (B=ones) on the matrix pipe.
// MODE 0: + gemm1 vs register-prefetched W1T ping/pong (1 barrier/kc).
// MODE 1: head-mean fp32 out.
template<int MODE>
__global__ __launch_bounds__(256, 4) void k_attn_fused(
    const float* __restrict__ adj, const float* __restrict__ s,
    const float* __restrict__ dTg, const float* __restrict__ maxd,
    const _Float16* __restrict__ hpT,
    const _Float16* __restrict__ W1T,
    const float* __restrict__ a_src, const float* __restrict__ a_dst,
    float* __restrict__ s_out, float* __restrict__ dTg_out,
    _Float16* __restrict__ hpT_out, float* __restrict__ o_f)
{
    __shared__ __align__(16) char smem[32768];
    _Float16* hT = (_Float16*)smem;            // [64][64] swizzled fp16, 8KB

    int blk = blockIdx.x;
    int vb = ((blk & 7) << 7) | (blk >> 3);    // XCD swizzle: 4 batches/XCD
    int b = vb >> 5, i0 = (vb & 31) << 4;
    int row0 = vb * 16;                        // = b*512 + i0
    int t = threadIdx.x, lane = t & 63, w = t >> 6;
    int cn = lane & 15, rq = lane >> 4;
    int h0 = 2 * w, h1 = h0 + 1;
    int myrow = i0 + cn;

    float sv0 = s[((size_t)b * NN + myrow) * 8 + h0];
    float sv1 = s[((size_t)b * NN + myrow) * 8 + h1];
    float M0 = fmaxf(sv0 + maxd[b * 8 + h0], 0.f);
    float M1 = fmaxf(sv1 + maxd[b * 8 + h1], 0.f);

    const float* arow = adj + ((size_t)b * NN + myrow) * NN;
    const float* dg0 = dTg + ((size_t)b * 8 + h0) * NN;
    const float* dg1 = dTg + ((size_t)b * 8 + h1) * NN;
    const _Float16* hb = hpT + (size_t)b * 64 * NN;

    // staging geometry: thread covers rows f0 and f0+32, granule g0
    int f0 = t >> 3, g0 = t & 7;
    int f1 = f0 + 32;                          // (f1&7)==(f0&7)
    int sw = ((g0 ^ (f0 & 7)) * 8);
    int sw0 = f0 * 64 + sw, sw1 = f1 * 64 + sw;

    f16x8 ones;
#pragma unroll
    for (int e = 0; e < 8; ++e) ones[e] = (_Float16)1.0f;

    f32x4 acc[2][4], accrs[2];
#pragma unroll
    for (int hh = 0; hh < 2; ++hh) {
#pragma unroll
        for (int e = 0; e < 4; ++e) accrs[hh][e] = 0.f;
#pragma unroll
        for (int ft = 0; ft < 4; ++ft)
#pragma unroll
            for (int e = 0; e < 4; ++e) acc[hh][ft][e] = 0.f;
    }

    // prologue: issue hT loads for chunk 0
    uint4 rH0 = *(const uint4*)(hb + (size_t)f0 * 512 + g0 * 8);
    uint4 rH1 = *(const uint4*)(hb + (size_t)f1 * 512 + g0 * 8);

    for (int jcx = 0; jcx < 8; ++jcx) {
        int jc = jcx * 64;
        // ---- issue adj/d loads for THIS chunk (consumed after the barrier)
        float aa[2][8], dd0[2][8], dd1[2][8];
#pragma unroll
        for (int ks = 0; ks < 2; ++ks) {
            int j0 = jc + ks * 32 + rq * 8;
            *(float4*)&aa[ks][0]  = *(const float4*)(arow + j0);
            *(float4*)&aa[ks][4]  = *(const float4*)(arow + j0 + 4);
            *(float4*)&dd0[ks][0] = *(const float4*)(dg0 + j0);
            *(float4*)&dd0[ks][4] = *(const float4*)(dg0 + j0 + 4);
            *(float4*)&dd1[ks][0] = *(const float4*)(dg1 + j0);
            *(float4*)&dd1[ks][4] = *(const float4*)(dg1 + j0 + 4);
        }
        // ---- commit prefetched hT (waits only the rH loads, issued a chunk ago)
        *(uint4*)&hT[sw0] = rH0;
        *(uint4*)&hT[sw1] = rH1;
        __syncthreads();
        // ---- issue hT loads for NEXT chunk (consumed at next commit)
        if (jcx < 7) {
            rH0 = *(const uint4*)(hb + (size_t)f0 * 512 + jc + 64 + g0 * 8);
            rH1 = *(const uint4*)(hb + (size_t)f1 * 512 + jc + 64 + g0 * 8);
        }
        // ---- P-build (packed) + MFMA
#pragma unroll
        for (int ks = 0; ks < 2; ++ks) {
            int j0 = jc + ks * 32 + rq * 8;
            int rel = myrow - j0;              // self-loop at e == rel
            AF aA, aB;
#pragma unroll
            for (int e = 0; e < 8; e += 2) {
                float pA[2], pB[2];
#pragma unroll
                for (int q = 0; q < 2; ++q) {
                    int ee = e + q;
                    bool con = (aa[ks][ee] != 0.f) || (ee == rel);
                    float e0 = sv0 + dd0[ks][ee];
                    float l0 = fmaxf(e0, 0.2f * e0);
                    float p0 = __expf(l0 - M0);
                    pA[q] = (con && l0 != 0.f) ? p0 : 0.f;   // mask + ==0 quirk
                    float e1 = sv1 + dd1[ks][ee];
                    float l1 = fmaxf(e1, 0.2f * e1);
                    float p1 = __expf(l1 - M1);
                    pB[q] = (con && l1 != 0.f) ? p1 : 0.f;
                }
                fp16x2 ka = __builtin_amdgcn_cvt_pkrtz(pA[0], pA[1]);
                fp16x2 kb = __builtin_amdgcn_cvt_pkrtz(pB[0], pB[1]);
                aA.u[e >> 1] = __builtin_bit_cast(unsigned int, ka);
                aB.u[e >> 1] = __builtin_bit_cast(unsigned int, kb);
            }
            accrs[0] = MFMA16(aA.v, ones, accrs[0]);
            accrs[1] = MFMA16(aB.v, ones, accrs[1]);
#pragma unroll
            for (int ft = 0; ft < 4; ++ft) {
                int f = ft * 16 + cn;
                f16x8 bh = *(const f16x8*)&hT[f * 64 + (((ks * 4 + rq) ^ (f & 7)) * 8)];
                acc[0][ft] = MFMA16(aA.v, bh, acc[0][ft]);
                acc[1][ft] = MFMA16(aB.v, bh, acc[1][ft]);
            }
        }
        __syncthreads();
    }

    float invr[2][4];
#pragma unroll
    for (int hh = 0; hh < 2; ++hh)
#pragma unroll
        for (int r = 0; r < 4; ++r) invr[hh][r] = 1.0f / accrs[hh][r];

    if (MODE == 0) {
        // ---- x1 tiles (normalized + ELU) into LDS, A-layout, XOR-swizzled
        _Float16* x1all = (_Float16*)(smem + 8192);    // [8 heads][16*64], 16KB
#pragma unroll
        for (int hh = 0; hh < 2; ++hh) {
            int h = h0 + hh;
#pragma unroll
            for (int ft = 0; ft < 4; ++ft)
#pragma unroll
                for (int r = 0; r < 4; ++r) {
                    int il = rq * 4 + r;
                    float v = acc[hh][ft][r] * invr[hh][r];
                    v = v > 0.f ? v : __expf(v) - 1.f;   // ELU
                    int f = ft * 16 + cn;
                    x1all[h * 1024 + il * 64 + (((f >> 3) ^ (il & 7)) * 8) + (f & 7)] =
                        (_Float16)v;
                }
        }

        // ---- gemm1: A from LDS x1all, B = W1T ping/pong, register-prefetched.
        // Global W1T is ALREADY swizzled -> straight physical copies.
        _Float16* Bst[2] = { (_Float16*)smem, (_Float16*)(smem + 24576) };
        {   // stage kc=0 directly (hT dead after final K-loop barrier)
#pragma unroll
            for (int u = 0; u < 2; ++u) {
                int idx = t + u * 256;
                *(uint4*)&Bst[0][idx * 8] =
                    *(const uint4*)(W1T + (size_t)(idx >> 3) * 512 + (idx & 7) * 8);
            }
        }
        f32x4 g1;
#pragma unroll
        for (int e = 0; e < 4; ++e) g1[e] = 0.f;
        uint4 rB0, rB1;
        for (int kc = 0; kc < 8; ++kc) {
            int cur = kc & 1;
            if (kc < 7) {   // issue next chunk's loads before the barrier
                rB0 = *(const uint4*)(W1T + (size_t)(t >> 3) * 512 + (kc + 1) * 64 + (t & 7) * 8);
                rB1 = *(const uint4*)(W1T + (size_t)((t + 256) >> 3) * 512 + (kc + 1) * 64 + (t & 7) * 8);
            }
            __syncthreads();   // Bst[cur] committed (prev iter) now visible
#pragma unroll
            for (int ks = 0; ks < 2; ++ks) {
                int pa = (((ks * 4 + rq) ^ (cn & 7)) * 8);
                f16x8 ah = *(const f16x8*)&x1all[kc * 1024 + cn * 64 + pa];
                int nn = w * 16 + cn;
                f16x8 bh = *(const f16x8*)&Bst[cur][nn * 64 + (((ks * 4 + rq) ^ (nn & 7)) * 8)];
                g1 = MFMA16(ah, bh, g1);
            }
            if (kc < 7) {   // commit into the idle buffer (no barrier needed)
                *(uint4*)&Bst[cur ^ 1][t * 8] = rB0;
                *(uint4*)&Bst[cur ^ 1][(t + 256) * 8] = rB1;
            }
        }
        __syncthreads();                       // x1all dead -> reuse region
        float* ctile = (float*)(smem + 8192);  // 4224 B
        float* asd_f = (float*)(smem + 16384); // 4096 B
#pragma unroll
        for (int r = 0; r < 4; ++r)
            ctile[(rq * 4 + r) * 66 + w * 16 + cn] = g1[r];
        ((float4*)asd_f)[t] = (t < 128) ? ((const float4*)a_src)[t]
                                        : ((const float4*)a_dst)[t - 128];
        __syncthreads();
        epi_sd_hpt(ctile, asd_f, row0, t, s_out, dTg_out, hpT_out);
    } else {
        float* red = (float*)smem;             // [4][16][64] fp32 = 16 KB
#pragma unroll
        for (int ft = 0; ft < 4; ++ft)
#pragma unroll
            for (int r = 0; r < 4; ++r) {
                int il = rq * 4 + r;
                float v = acc[0][ft][r] * invr[0][r]
                        + acc[1][ft][r] * invr[1][r];
                red[(w * 16 + il) * 64 + ft * 16 + cn] = v;
            }
        __syncthreads();
#pragma unroll
        for (int u = 0; u < 4; ++u) {
            int idx = t + u * 256;
            int il = idx >> 6, f = idx & 63;
            float sum = red[il * 64 + f] + red[(16 + il) * 64 + f]
                      + red[(32 + il) * 64 + f] + red[(48 + il) * 64 + f];
            o_f[((size_t)b * NN + i0 + il) * 64 + f] = sum * 0.125f;
        }
    }
}

extern "C" void kernel_launch(void* const* d_in, const int* in_sizes, int n_in,
                              void* d_out, int out_size, void* d_ws, size_t ws_size,
                              hipStream_t stream) {
    const float* x      = (const float*)d_in[0];
    const float* adj    = (const float*)d_in[1];
    const float* W0     = (const float*)d_in[4];
    const float* a_src0 = (const float*)d_in[5];
    const float* a_dst0 = (const float*)d_in[6];
    const float* W1     = (const float*)d_in[7];
    const float* a_src1 = (const float*)d_in[8];
    const float* a_dst1 = (const float*)d_in[9];
    float* out = (float*)d_out;

    float* ws = (float*)d_ws;
    const size_t R = (size_t)BB * NN;            // 16384 rows
    float* s0    = ws;                           // R*8
    float* dTg0  = s0 + R * 8;                   // 32*8*512
    float* s1    = dTg0 + (size_t)BB * 8 * NN;
    float* dTg1  = s1 + R * 8;
    float* maxd0 = dTg1 + (size_t)BB * 8 * NN;   // 256
    float* maxd1 = maxd0 + 256;                  // 256
    _Float16* hp0T = (_Float16*)(maxd1 + 256);   // 32*64*512
    _Float16* hp1T = hp0T + (size_t)BB * 64 * NN;
    _Float16* W0T  = hp1T + (size_t)BB * 64 * NN;   // 64*64
    _Float16* W1T  = W0T + (size_t)64 * 64;         // 64*512

    k_wt_prep<<<18, 256, 0, stream>>>(W0, W0T, W1, W1T);
    k_gemm0<<<1024, 256, 0, stream>>>(x, W0T, a_src0, a_dst0, s0, dTg0, hp0T);
    k_maxd<<<256, 256, 0, stream>>>(dTg0, maxd0);
    k_attn_fused<0><<<1024, 256, 0, stream>>>(adj, s0, dTg0, maxd0, hp0T,
                                              W1T, a_src1, a_dst1,
                                              s1, dTg1, hp1T, nullptr);
    k_maxd<<<256, 256, 0, stream>>>(dTg1, maxd1);
    k_attn_fused<1><<<1024, 256, 0, stream>>>(adj, s1, dTg1, maxd1, hp1T,
                                              nullptr, nullptr, nullptr,
                                              nullptr, nullptr, nullptr, out);
}